// Round 4
// baseline (414.941 us; speedup 1.0000x reference)
//
#include <hip/hip_runtime.h>
#include <hip/hip_bf16.h>

#define BATCH 64
#define SEQ 729
#define DIM 64
#define NT 12      // ceil(729/64)
#define KSTR 72    // u16 LDS stride for Ks/Qs rows
#define VSTR 66    // u16 LDS stride for Vs [d][k]: odd-dword stride -> no 8-way write conflict
#define PSTR 68    // dword LDS stride for Pf (mask/P fp32), 16B-aligned rows

typedef __attribute__((ext_vector_type(8))) short bf16x8;
typedef __attribute__((ext_vector_type(4))) float f32x4;
// 4B-aligned vector views (global rows of length 729 are only dword-aligned)
typedef int   i32x4a __attribute__((ext_vector_type(4), aligned(4)));
typedef float f32x4a __attribute__((ext_vector_type(4), aligned(4)));

// RNE f32->bf16 via HW v_cvt_pk_bf16_f32
__device__ __forceinline__ void st4bf(unsigned short* p, float a, float b, float c, float d) {
    __hip_bfloat162 lo = __float22bfloat162_rn(float2{a, b});
    __hip_bfloat162 hi = __float22bfloat162_rn(float2{c, d});
    unsigned int ulo = *(unsigned int*)&lo;
    unsigned int uhi = *(unsigned int*)&hi;
    *(unsigned long long*)p = (unsigned long long)ulo | ((unsigned long long)uhi << 32);
}
__device__ __forceinline__ unsigned short f2bf1(float f) {
    __hip_bfloat16 h = __float2bfloat16(f);
    return *(unsigned short*)&h;
}

// tanh(x) = 1 - 2/(exp2(2x*log2e)+1)
__device__ __forceinline__ float fast_tanh(float x) {
    float e = __builtin_amdgcn_exp2f(x * 2.88539008177792681f);
    return 1.0f - 2.0f * __builtin_amdgcn_rcpf(e + 1.0f);
}

struct Tile {
    float4 kr[4];
    float4 vr[4];
    i32x4a mr[4];
};

__global__ __launch_bounds__(256, 3) void attn_kernel(
    const float* __restrict__ Qg, const float* __restrict__ Kg,
    const float* __restrict__ Vg, const int* __restrict__ Mg,
    float* __restrict__ Og, float* __restrict__ Ag)
{
    __shared__ unsigned short Ks[64 * KSTR];  // [k][d] bf16
    __shared__ unsigned short Vs[64 * VSTR];  // [d][k] bf16 (transposed)
    __shared__ unsigned short Qs[64 * KSTR];  // Q bf16, then P bf16 (wave-private rows)
    __shared__ float Pf[64 * PSTR];           // mask int, then P fp32 (wave-private rows)
    int* Mint = (int*)Pf;

    const int tid = threadIdx.x;
    const int q0  = blockIdx.x * 64;
    const int b   = blockIdx.y;

    const float* Qb = Qg + (size_t)b * SEQ * DIM;
    const float* Kb = Kg + (size_t)b * SEQ * DIM;
    const float* Vb = Vg + (size_t)b * SEQ * DIM;
    const int*   Mb = Mg + (size_t)b * SEQ * SEQ;
    float* Ob = Og + (size_t)b * SEQ * DIM;
    float* Ab = Ag + (size_t)b * SEQ * SEQ;

    const int lane = tid & 63;
    const int quad = lane >> 4;
    const int l15  = lane & 15;
    const int qrow = (tid >> 6) * 16;      // wave's q-strip base (local)

    // staging geometry: 16 consecutive threads cover one row (256B segments)
    const int rr = tid >> 4;               // row group 0..15 (+16*i)
    const int cc = (tid & 15) * 4;         // col (floats)
    const int vd0 = (tid & 15) * 4;        // V: dims
    const int vk0 = (tid >> 4) * 4;        // V: k rows
    // wave-private mask/P rows: 16 lanes cover one row's 64 cols
    const int prow = qrow + (lane >> 4);   // + 4*i
    const int pcol = (lane & 15) * 4;

    auto load_tile = [&](Tile& T, int kt) {
        const int k0n = kt * 64;
        #pragma unroll
        for (int i = 0; i < 4; ++i) {
            int gk = k0n + rr + 16 * i;
            T.kr[i] = (gk < SEQ) ? *(const float4*)(Kb + gk * DIM + cc)
                                 : float4{0, 0, 0, 0};
        }
        #pragma unroll
        for (int i = 0; i < 4; ++i) {
            int gk = k0n + vk0 + i;
            T.vr[i] = (gk < SEQ) ? *(const float4*)(Vb + gk * DIM + vd0)
                                 : float4{0, 0, 0, 0};
        }
        #pragma unroll
        for (int i = 0; i < 4; ++i) {
            int gq = q0 + prow + 4 * i;
            int gk = k0n + pcol;
            if (gq < SEQ && gk + 3 < SEQ) {
                T.mr[i] = *(const i32x4a*)(Mb + (size_t)gq * SEQ + gk);
            } else if (gq < SEQ) {
                i32x4a t;
                #pragma unroll
                for (int e = 0; e < 4; ++e)
                    t[e] = (gk + e < SEQ) ? Mb[(size_t)gq * SEQ + gk + e] : 0;
                T.mr[i] = t;
            } else {
                T.mr[i] = i32x4a{0, 0, 0, 0};
            }
        }
    };

    auto drain_tile = [&](Tile& T) {
        #pragma unroll
        for (int i = 0; i < 4; ++i)
            st4bf(&Ks[(rr + 16 * i) * KSTR + cc],
                  T.kr[i].x, T.kr[i].y, T.kr[i].z, T.kr[i].w);
        #pragma unroll
        for (int j = 0; j < 4; ++j) {
            float v0 = j==0?T.vr[0].x:j==1?T.vr[0].y:j==2?T.vr[0].z:T.vr[0].w;
            float v1 = j==0?T.vr[1].x:j==1?T.vr[1].y:j==2?T.vr[1].z:T.vr[1].w;
            float v2 = j==0?T.vr[2].x:j==1?T.vr[2].y:j==2?T.vr[2].z:T.vr[2].w;
            float v3 = j==0?T.vr[3].x:j==1?T.vr[3].y:j==2?T.vr[3].z:T.vr[3].w;
            st4bf(&Vs[(vd0 + j) * VSTR + vk0], v0, v1, v2, v3);
        }
        #pragma unroll
        for (int i = 0; i < 4; ++i)
            *(i32x4a*)&Mint[(prow + 4 * i) * PSTR + pcol] = T.mr[i];  // wave-private
    };

    // ---- preamble: Q loads first (so staging Q waits only on them), then T0,T1 ----
    float4 qx[4];
    #pragma unroll
    for (int i = 0; i < 4; ++i) {
        int gq = q0 + rr + 16 * i;
        qx[i] = (gq < SEQ) ? *(const float4*)(Qb + gq * DIM + cc)
                           : float4{0, 0, 0, 0};
    }
    Tile TA, TB;
    load_tile(TA, 0);
    load_tile(TB, 1);

    #pragma unroll
    for (int i = 0; i < 4; ++i)
        st4bf(&Qs[(rr + 16 * i) * KSTR + cc], qx[i].x, qx[i].y, qx[i].z, qx[i].w);
    __syncthreads();

    // hoist loop-invariant Q fragments; Qs becomes the P bf16 buffer
    const bf16x8 aq0 = *(const bf16x8*)&Qs[(qrow + l15) * KSTR + quad * 8];
    const bf16x8 aq1 = *(const bf16x8*)&Qs[(qrow + l15) * KSTR + 32 + quad * 8];

    f32x4 oacc[4];
    #pragma unroll
    for (int dt = 0; dt < 4; ++dt) {
        oacc[dt][0]=0.f; oacc[dt][1]=0.f; oacc[dt][2]=0.f; oacc[dt][3]=0.f;
    }

    auto compute_tile = [&](int kt) {
        const int k0 = kt * 64;
        // ---- QK^T ----
        f32x4 sacc[4];
        #pragma unroll
        for (int nt2 = 0; nt2 < 4; ++nt2) {
            bf16x8 bk0 = *(const bf16x8*)&Ks[(nt2 * 16 + l15) * KSTR + quad * 8];
            bf16x8 bk1 = *(const bf16x8*)&Ks[(nt2 * 16 + l15) * KSTR + 32 + quad * 8];
            f32x4 c; c[0]=0.f; c[1]=0.f; c[2]=0.f; c[3]=0.f;
            c = __builtin_amdgcn_mfma_f32_16x16x32_bf16(aq0, bk0, c, 0, 0, 0);
            c = __builtin_amdgcn_mfma_f32_16x16x32_bf16(aq1, bk1, c, 0, 0, 0);
            sacc[nt2] = c;
        }
        // ---- scale, mask (LDS), tanh, zero-diag; write P fp32 + bf16 ----
        #pragma unroll
        for (int nt2 = 0; nt2 < 4; ++nt2) {
            int col = nt2 * 16 + l15;
            int gk  = k0 + col;
            #pragma unroll
            for (int r = 0; r < 4; ++r) {
                int qloc = qrow + quad * 4 + r;
                int gq = q0 + qloc;
                int m = Mint[qloc * PSTR + col];
                float sv = sacc[nt2][r] * 0.125f;       // 1/sqrt(64)
                bool msk = (m == 0);
                float p = fast_tanh(msk ? -1e9f : sv);
                if (msk) p = -1.0f;
                if (gq == gk) p = 0.0f;                 // ignore_diag
                if (gq >= SEQ || gk >= SEQ) p = 0.0f;   // padding
                Pf[qloc * PSTR + col] = p;              // in-place over mask
                Qs[qloc * KSTR + col] = f2bf1(p);
            }
        }
        // ---- attention write: wave-private rows, row-contiguous float4 ----
        #pragma unroll
        for (int i = 0; i < 4; ++i) {
            int row = prow + 4 * i;
            int gq  = q0 + row;
            int gk  = k0 + pcol;
            f32x4 pv = *(const f32x4*)&Pf[row * PSTR + pcol];
            if (gq < SEQ) {
                if (gk + 3 < SEQ) {
                    *(f32x4a*)(Ab + (size_t)gq * SEQ + gk) = pv;
                } else {
                    #pragma unroll
                    for (int e = 0; e < 4; ++e)
                        if (gk + e < SEQ) Ab[(size_t)gq * SEQ + gk + e] = pv[e];
                }
            }
        }
        // ---- PV ----
        const bf16x8 ap0 = *(const bf16x8*)&Qs[(qrow + l15) * KSTR + quad * 8];
        const bf16x8 ap1 = *(const bf16x8*)&Qs[(qrow + l15) * KSTR + 32 + quad * 8];
        #pragma unroll
        for (int dt = 0; dt < 4; ++dt) {
            bf16x8 bv0 = *(const bf16x8*)&Vs[(dt * 16 + l15) * VSTR + quad * 8];
            bf16x8 bv1 = *(const bf16x8*)&Vs[(dt * 16 + l15) * VSTR + 32 + quad * 8];
            oacc[dt] = __builtin_amdgcn_mfma_f32_16x16x32_bf16(ap0, bv0, oacc[dt], 0, 0, 0);
            oacc[dt] = __builtin_amdgcn_mfma_f32_16x16x32_bf16(ap1, bv1, oacc[dt], 0, 0, 0);
        }
    };

    // ---- main loop, unrolled x2: prefetch distance 2 (drain never waits) ----
    for (int kt = 0; kt < NT; kt += 2) {
        __syncthreads();                 // prev tile's Ks/Vs readers done
        drain_tile(TA);                  // tile kt (loaded 2 phases ago)
        __syncthreads();
        if (kt + 2 < NT) load_tile(TA, kt + 2);
        compute_tile(kt);

        __syncthreads();
        drain_tile(TB);                  // tile kt+1
        __syncthreads();
        if (kt + 3 < NT) load_tile(TB, kt + 3);
        compute_tile(kt + 1);
    }

    // ---- epilogue: stage out tile in Pf (wave-private), write float4 ----
    #pragma unroll
    for (int dt = 0; dt < 4; ++dt)
        #pragma unroll
        for (int r = 0; r < 4; ++r)
            Pf[(qrow + quad * 4 + r) * PSTR + dt * 16 + l15] = oacc[dt][r];
    #pragma unroll
    for (int i = 0; i < 4; ++i) {
        int row = prow + 4 * i;
        int gq  = q0 + row;
        f32x4 ov = *(const f32x4*)&Pf[row * PSTR + pcol];
        if (gq < SEQ) *(f32x4*)(Ob + (size_t)gq * DIM + pcol) = ov;  // 16B-aligned
    }
}

extern "C" void kernel_launch(void* const* d_in, const int* in_sizes, int n_in,
                              void* d_out, int out_size, void* d_ws, size_t ws_size,
                              hipStream_t stream) {
    const float* Q = (const float*)d_in[0];
    const float* K = (const float*)d_in[1];
    const float* V = (const float*)d_in[2];
    const int*   M = (const int*)d_in[3];
    float* Out  = (float*)d_out;
    float* Attn = Out + (size_t)BATCH * SEQ * DIM;   // tuple order: (out, attention)
    dim3 grid(NT, BATCH);
    attn_kernel<<<grid, 256, 0, stream>>>(Q, K, V, M, Out, Attn);
}

// Round 5
// 381.249 us; speedup vs baseline: 1.0884x; 1.0884x over previous
//
#include <hip/hip_runtime.h>
#include <hip/hip_bf16.h>

#define BATCH 64
#define SEQ 729
#define DIM 64
#define NT 12      // ceil(729/64)
#define KSTR 72    // u16 LDS stride for Ks/Qs rows
#define VSTR 66    // u16 LDS stride for Vs [d][k]: odd-dword stride -> 4-way max
#define MSTR 72    // u16 LDS stride for mask tile
#define OSTR 68    // dword stride for epilogue out staging

typedef __attribute__((ext_vector_type(8))) short bf16x8;
typedef __attribute__((ext_vector_type(4))) float f32x4;
typedef int   i32x4a __attribute__((ext_vector_type(4), aligned(4)));
typedef float f32x4a __attribute__((ext_vector_type(4), aligned(4)));

// RNE f32->bf16 via HW v_cvt_pk_bf16_f32
__device__ __forceinline__ void st4bf(unsigned short* p, float a, float b, float c, float d) {
    __hip_bfloat162 lo = __float22bfloat162_rn(float2{a, b});
    __hip_bfloat162 hi = __float22bfloat162_rn(float2{c, d});
    unsigned int ulo = *(unsigned int*)&lo;
    unsigned int uhi = *(unsigned int*)&hi;
    *(unsigned long long*)p = (unsigned long long)ulo | ((unsigned long long)uhi << 32);
}
__device__ __forceinline__ unsigned short f2bf1(float f) {
    __hip_bfloat16 h = __float2bfloat16(f);
    return *(unsigned short*)&h;
}
__device__ __forceinline__ float bf2f(unsigned short u) {
    return __uint_as_float((unsigned int)u << 16);
}

// tanh(x) = 1 - 2/(exp2(2x*log2e)+1)
__device__ __forceinline__ float fast_tanh(float x) {
    float e = __builtin_amdgcn_exp2f(x * 2.88539008177792681f);
    return 1.0f - 2.0f * __builtin_amdgcn_rcpf(e + 1.0f);
}

// -------- spill-proof load/drain: macros over plain local arrays ----------
#define LOAD_TILE(kr, vr, mu, kt_) do {                                        \
    const int _k0n = (kt_) * 64;                                               \
    _Pragma("unroll")                                                          \
    for (int _i = 0; _i < 4; ++_i) {                                           \
        int _gk = _k0n + rr + 16 * _i;                                         \
        kr[_i] = (_gk < SEQ) ? *(const float4*)(Kb + _gk * DIM + cc)           \
                             : float4{0, 0, 0, 0};                             \
    }                                                                          \
    _Pragma("unroll")                                                          \
    for (int _i = 0; _i < 4; ++_i) {                                           \
        int _gk = _k0n + vk0 + _i;                                             \
        vr[_i] = (_gk < SEQ) ? *(const float4*)(Vb + _gk * DIM + vd0)          \
                             : float4{0, 0, 0, 0};                             \
    }                                                                          \
    _Pragma("unroll")                                                          \
    for (int _i = 0; _i < 4; ++_i) {                                           \
        int _gq = q0 + prow + 4 * _i;                                          \
        int _gk = _k0n + pcol;                                                 \
        i32x4a _t;                                                             \
        if (_gq < SEQ && _gk + 3 < SEQ) {                                      \
            _t = *(const i32x4a*)(Mb + (size_t)_gq * SEQ + _gk);               \
        } else if (_gq < SEQ) {                                                \
            _Pragma("unroll")                                                  \
            for (int _e = 0; _e < 4; ++_e)                                     \
                _t[_e] = (_gk + _e < SEQ) ? Mb[(size_t)_gq * SEQ + _gk + _e] : 0; \
        } else { _t = i32x4a{0, 0, 0, 0}; }                                    \
        mu[_i] = (unsigned long long)(unsigned short)_t[0]                     \
               | ((unsigned long long)(unsigned short)_t[1] << 16)             \
               | ((unsigned long long)(unsigned short)_t[2] << 32)             \
               | ((unsigned long long)(unsigned short)_t[3] << 48);            \
    }                                                                          \
} while (0)

#define DRAIN_TILE(kr, vr, mu) do {                                            \
    _Pragma("unroll")                                                          \
    for (int _i = 0; _i < 4; ++_i)                                             \
        st4bf(&Ks[(rr + 16 * _i) * KSTR + cc],                                 \
              kr[_i].x, kr[_i].y, kr[_i].z, kr[_i].w);                         \
    _Pragma("unroll")                                                          \
    for (int _j = 0; _j < 4; ++_j) {                                           \
        float _v0 = _j==0?vr[0].x:_j==1?vr[0].y:_j==2?vr[0].z:vr[0].w;         \
        float _v1 = _j==0?vr[1].x:_j==1?vr[1].y:_j==2?vr[1].z:vr[1].w;         \
        float _v2 = _j==0?vr[2].x:_j==1?vr[2].y:_j==2?vr[2].z:vr[2].w;         \
        float _v3 = _j==0?vr[3].x:_j==1?vr[3].y:_j==2?vr[3].z:vr[3].w;         \
        st4bf(&Vs[(vd0 + _j) * VSTR + vk0], _v0, _v1, _v2, _v3);               \
    }                                                                          \
    _Pragma("unroll")                                                          \
    for (int _i = 0; _i < 4; ++_i)                                             \
        *(unsigned long long*)&Ms[(prow + 4 * _i) * MSTR + pcol] = mu[_i];     \
} while (0)

__global__ __launch_bounds__(256, 3) void attn_kernel(
    const float* __restrict__ Qg, const float* __restrict__ Kg,
    const float* __restrict__ Vg, const int* __restrict__ Mg,
    float* __restrict__ Og, float* __restrict__ Ag)
{
    // unified LDS: Ks | Vs | Qs | Ms ; epilogue reuses [0, 17664) as f32 stage
    __shared__ __align__(16) char SMEM[64 * KSTR * 2 + 64 * VSTR * 2 +
                                       64 * KSTR * 2 + 64 * MSTR * 2];
    unsigned short* Ks = (unsigned short*)SMEM;                       // 9216 B
    unsigned short* Vs = (unsigned short*)(SMEM + 9216);              // 8448 B
    unsigned short* Qs = (unsigned short*)(SMEM + 17664);             // 9216 B
    unsigned short* Ms = (unsigned short*)(SMEM + 26880);             // 9216 B
    float* Ostage = (float*)SMEM;                                     // 17408 B

    const int tid = threadIdx.x;
    const int q0  = blockIdx.x * 64;
    const int b   = blockIdx.y;

    const float* Qb = Qg + (size_t)b * SEQ * DIM;
    const float* Kb = Kg + (size_t)b * SEQ * DIM;
    const float* Vb = Vg + (size_t)b * SEQ * DIM;
    const int*   Mb = Mg + (size_t)b * SEQ * SEQ;
    float* Ob = Og + (size_t)b * SEQ * DIM;
    float* Ab = Ag + (size_t)b * SEQ * SEQ;

    const int lane = tid & 63;
    const int quad = lane >> 4;
    const int l15  = lane & 15;
    const int qrow = (tid >> 6) * 16;      // wave's q-strip base (local)

    // staging geometry: 16 consecutive threads cover one row (256B segments)
    const int rr = tid >> 4;               // row group 0..15 (+16*i)
    const int cc = (tid & 15) * 4;         // col (floats)
    const int vd0 = (tid & 15) * 4;        // V: dims
    const int vk0 = (tid >> 4) * 4;        // V: k rows
    // wave-private rows: 16 lanes cover one row's 64 cols
    const int prow = qrow + (lane >> 4);   // + 4*i
    const int pcol = (lane & 15) * 4;

    // ---- payload registers: two independent sets (distance-2 pipeline) ----
    float4 krA[4], vrA[4], krB[4], vrB[4];
    unsigned long long muA[4], muB[4];

    // ---- preamble: Q loads first, then tiles 0 and 1 ----
    float4 qx[4];
    #pragma unroll
    for (int i = 0; i < 4; ++i) {
        int gq = q0 + rr + 16 * i;
        qx[i] = (gq < SEQ) ? *(const float4*)(Qb + gq * DIM + cc)
                           : float4{0, 0, 0, 0};
    }
    LOAD_TILE(krA, vrA, muA, 0);
    LOAD_TILE(krB, vrB, muB, 1);

    #pragma unroll
    for (int i = 0; i < 4; ++i)
        st4bf(&Qs[(rr + 16 * i) * KSTR + cc], qx[i].x, qx[i].y, qx[i].z, qx[i].w);
    __syncthreads();

    // hoist loop-invariant Q fragments; Qs becomes the P bf16 buffer
    const bf16x8 aq0 = *(const bf16x8*)&Qs[(qrow + l15) * KSTR + quad * 8];
    const bf16x8 aq1 = *(const bf16x8*)&Qs[(qrow + l15) * KSTR + 32 + quad * 8];

    f32x4 oacc[4];
    #pragma unroll
    for (int dt = 0; dt < 4; ++dt) {
        oacc[dt][0]=0.f; oacc[dt][1]=0.f; oacc[dt][2]=0.f; oacc[dt][3]=0.f;
    }

    auto compute_tile = [&](int kt) {
        const int k0 = kt * 64;
        // ---- QK^T ----
        f32x4 sacc[4];
        #pragma unroll
        for (int nt2 = 0; nt2 < 4; ++nt2) {
            bf16x8 bk0 = *(const bf16x8*)&Ks[(nt2 * 16 + l15) * KSTR + quad * 8];
            bf16x8 bk1 = *(const bf16x8*)&Ks[(nt2 * 16 + l15) * KSTR + 32 + quad * 8];
            f32x4 c; c[0]=0.f; c[1]=0.f; c[2]=0.f; c[3]=0.f;
            c = __builtin_amdgcn_mfma_f32_16x16x32_bf16(aq0, bk0, c, 0, 0, 0);
            c = __builtin_amdgcn_mfma_f32_16x16x32_bf16(aq1, bk1, c, 0, 0, 0);
            sacc[nt2] = c;
        }
        // ---- scale, mask (LDS u16), tanh, zero-diag; write P bf16 ----
        #pragma unroll
        for (int nt2 = 0; nt2 < 4; ++nt2) {
            int col = nt2 * 16 + l15;
            int gk  = k0 + col;
            #pragma unroll
            for (int r = 0; r < 4; ++r) {
                int qloc = qrow + quad * 4 + r;
                int gq = q0 + qloc;
                unsigned short m = Ms[qloc * MSTR + col];
                float sv = sacc[nt2][r] * 0.125f;       // 1/sqrt(64)
                bool msk = (m == 0);
                float p = fast_tanh(msk ? -1e9f : sv);
                if (msk) p = -1.0f;
                if (gq == gk) p = 0.0f;                 // ignore_diag
                if (gq >= SEQ || gk >= SEQ) p = 0.0f;   // padding
                Qs[qloc * KSTR + col] = f2bf1(p);
            }
        }
        // ---- attention write from bf16 P (wave-private rows, float4 stores) ----
        #pragma unroll
        for (int i = 0; i < 4; ++i) {
            int row = prow + 4 * i;
            int gq  = q0 + row;
            int gk  = k0 + pcol;
            ushort4 pu = *(const ushort4*)&Qs[row * KSTR + pcol];
            f32x4 pv;
            pv[0] = bf2f(pu.x); pv[1] = bf2f(pu.y);
            pv[2] = bf2f(pu.z); pv[3] = bf2f(pu.w);
            if (gq < SEQ) {
                if (gk + 3 < SEQ) {
                    *(f32x4a*)(Ab + (size_t)gq * SEQ + gk) = pv;
                } else {
                    #pragma unroll
                    for (int e = 0; e < 4; ++e)
                        if (gk + e < SEQ) Ab[(size_t)gq * SEQ + gk + e] = pv[e];
                }
            }
        }
        // ---- PV ----
        const bf16x8 ap0 = *(const bf16x8*)&Qs[(qrow + l15) * KSTR + quad * 8];
        const bf16x8 ap1 = *(const bf16x8*)&Qs[(qrow + l15) * KSTR + 32 + quad * 8];
        #pragma unroll
        for (int dt = 0; dt < 4; ++dt) {
            bf16x8 bv0 = *(const bf16x8*)&Vs[(dt * 16 + l15) * VSTR + quad * 8];
            bf16x8 bv1 = *(const bf16x8*)&Vs[(dt * 16 + l15) * VSTR + 32 + quad * 8];
            oacc[dt] = __builtin_amdgcn_mfma_f32_16x16x32_bf16(ap0, bv0, oacc[dt], 0, 0, 0);
            oacc[dt] = __builtin_amdgcn_mfma_f32_16x16x32_bf16(ap1, bv1, oacc[dt], 0, 0, 0);
        }
    };

    // ---- main loop, unrolled x2: true prefetch distance 2 ----
    for (int kt = 0; kt < NT; kt += 2) {
        __syncthreads();                  // prev tile's LDS readers done
        DRAIN_TILE(krA, vrA, muA);        // tile kt, loaded ~2 phases ago
        __syncthreads();
        if (kt + 2 < NT) LOAD_TILE(krA, vrA, muA, kt + 2);
        compute_tile(kt);

        __syncthreads();
        DRAIN_TILE(krB, vrB, muB);        // tile kt+1
        __syncthreads();
        if (kt + 3 < NT) LOAD_TILE(krB, vrB, muB, kt + 3);
        compute_tile(kt + 1);
    }

    // ---- epilogue: stage out tile over retired Ks/Vs, write float4 ----
    __syncthreads();                      // last PV's Vs readers done
    #pragma unroll
    for (int dt = 0; dt < 4; ++dt)
        #pragma unroll
        for (int r = 0; r < 4; ++r)
            Ostage[(qrow + quad * 4 + r) * OSTR + dt * 16 + l15] = oacc[dt][r];
    #pragma unroll
    for (int i = 0; i < 4; ++i) {
        int row = prow + 4 * i;
        int gq  = q0 + row;
        f32x4 ov = *(const f32x4*)&Ostage[row * OSTR + pcol];
        if (gq < SEQ) *(f32x4*)(Ob + (size_t)gq * DIM + pcol) = ov;  // 16B-aligned
    }
}

extern "C" void kernel_launch(void* const* d_in, const int* in_sizes, int n_in,
                              void* d_out, int out_size, void* d_ws, size_t ws_size,
                              hipStream_t stream) {
    const float* Q = (const float*)d_in[0];
    const float* K = (const float*)d_in[1];
    const float* V = (const float*)d_in[2];
    const int*   M = (const int*)d_in[3];
    float* Out  = (float*)d_out;
    float* Attn = Out + (size_t)BATCH * SEQ * DIM;   // tuple order: (out, attention)
    dim3 grid(NT, BATCH);
    attn_kernel<<<grid, 256, 0, stream>>>(Q, K, V, M, Out, Attn);
}